// Round 10
// baseline (560.329 us; speedup 1.0000x reference)
//
#include <hip/hip_runtime.h>
#include <stdint.h>

#define BB   8
#define NN   2048
#define FIN  256
#define FOUT 128

using short8 = __attribute__((ext_vector_type(8))) short;
using f32x4  = __attribute__((ext_vector_type(4))) float;

__device__ __forceinline__ unsigned short rbf(float f) {
    return (unsigned short)((__float_as_uint(f) + 0x8000u) >> 16);
}

// Calibration: 2 probe MFMAs read off the true (row,col) label of each
// accumulator element (validated round 4). Epilogues index by these labels.
__device__ __forceinline__ void mfma_calib(int m, int quad, int* Mlab, int* Nlab) {
    short8 pa1, pb1, pa2, pb2;
    const short one = (short)0x3F80;            // bf16 1.0
    const short mb  = (short)rbf((float)m);     // bf16 m (exact, m<16)
#pragma unroll
    for (int j = 0; j < 8; ++j) { pa1[j] = 0; pa2[j] = 0; pb1[j] = mb; pb2[j] = one; }
    if (quad == 0) { pa1[0] = one; pa2[0] = mb; }
    f32x4 zz = {0.f, 0.f, 0.f, 0.f};
    f32x4 c1 = __builtin_amdgcn_mfma_f32_16x16x32_bf16(pa1, pb1, zz, 0, 0, 0);
    f32x4 c2 = __builtin_amdgcn_mfma_f32_16x16x32_bf16(pa2, pb2, zz, 0, 0, 0);
#pragma unroll
    for (int r = 0; r < 4; ++r) {
        Nlab[r] = ((int)c1[r]) & 15;
        Mlab[r] = ((int)c2[r]) & 15;
    }
}

// ---------------- W[256][128] fp32 -> wt[128][256] bf16 (W^T) --------------
__global__ __launch_bounds__(256) void gat_wt(const float* __restrict__ W,
                                              unsigned short* __restrict__ wt) {
    const int g  = blockIdx.x * 256 + threadIdx.x;
    const int k  = g >> 5;
    const int o4 = (g & 31) << 2;
    float4 wv = *(const float4*)(W + (k << 7) + o4);
    wt[((o4 + 0) << 8) + k] = rbf(wv.x);
    wt[((o4 + 1) << 8) + k] = rbf(wv.y);
    wt[((o4 + 2) << 8) + k] = rbf(wv.z);
    wt[((o4 + 3) << 8) + k] = rbf(wv.w);
}

// ---------------- stage 1: h = x@W via MFMA (16 rows/block) ----------------
__global__ __launch_bounds__(256) void gat_h3(
        const float* __restrict__ x, const unsigned short* __restrict__ wt,
        const float* __restrict__ a, unsigned short* __restrict__ ht,
        float* __restrict__ f1, float* __restrict__ f2) {
    __shared__ unsigned short xs[16][264];
    __shared__ float hs[16][132];
    const int bk   = blockIdx.x;
    const int R0   = bk << 4;
    const int b    = R0 >> 11;
    const int il0  = R0 & (NN - 1);
    const int tid  = threadIdx.x;
    const int w    = tid >> 6;
    const int lane = tid & 63;
    const int m    = lane & 15;
    const int quad = lane >> 4;

#pragma unroll
    for (int rr = 0; rr < 4; ++rr) {
        const int row = (w << 2) + rr;
        float4 xv = *(const float4*)(x + (size_t)(R0 + row) * FIN + (lane << 2));
        ushort4 c4;
        c4.x = rbf(xv.x); c4.y = rbf(xv.y); c4.z = rbf(xv.z); c4.w = rbf(xv.w);
        *(ushort4*)(&xs[row][lane << 2]) = c4;
    }
    int Mlab[4], Nlab[4];
    mfma_calib(m, quad, Mlab, Nlab);
    __syncthreads();

    f32x4 zz = {0.f, 0.f, 0.f, 0.f};
    f32x4 acc[2] = {zz, zz};
#pragma unroll
    for (int kc = 0; kc < 8; ++kc) {
        const int k0 = (kc << 5) + (quad << 3);
        short8 av = *(const short8*)(&xs[m][k0]);
#pragma unroll
        for (int t = 0; t < 2; ++t) {
            const int ot = (w << 1) + t;
            short8 bw = *(const short8*)(wt + (((ot << 4) + m) << 8) + k0);
            acc[t] = __builtin_amdgcn_mfma_f32_16x16x32_bf16(av, bw, acc[t], 0, 0, 0);
        }
    }
#pragma unroll
    for (int t = 0; t < 2; ++t)
#pragma unroll
        for (int r = 0; r < 4; ++r)
            hs[Mlab[r]][(((w << 1) + t) << 4) + Nlab[r]] = acc[t][r];
    __syncthreads();

    {
        const int i   = tid >> 4;
        const int seg = tid & 15;
        const int o0  = seg << 3;
        float s1 = 0.f, s2 = 0.f;
#pragma unroll
        for (int e = 0; e < 8; ++e) {
            float hv = hs[i][o0 + e];
            s1 = fmaf(hv, a[o0 + e], s1);
            s2 = fmaf(hv, a[FOUT + o0 + e], s2);
        }
        s1 += __shfl_xor(s1, 1); s1 += __shfl_xor(s1, 2);
        s1 += __shfl_xor(s1, 4); s1 += __shfl_xor(s1, 8);
        s2 += __shfl_xor(s2, 1); s2 += __shfl_xor(s2, 2);
        s2 += __shfl_xor(s2, 4); s2 += __shfl_xor(s2, 8);
        if (seg == 0) { f1[R0 + i] = s1; f2[R0 + i] = s2; }
    }
    {
        const int o  = tid >> 1;
        const int i8 = (tid & 1) << 3;
        short8 hv;
#pragma unroll
        for (int e = 0; e < 8; ++e) hv[e] = (short)rbf(hs[i8 + e][o]);
        *(short8*)(ht + ((size_t)((b << 7) + o) << 11) + il0 + i8) = hv;
    }
}

// ---------------- adj pack v2: int32 0/1 -> bitmask ------------------------
// Lane owns 32 contiguous ints (8 independent int4 loads in flight, no
// cross-lane ops), builds its own mask word; coalesced 256B word stores.
__global__ __launch_bounds__(256) void gat_pk(const int* __restrict__ adj,
                                              unsigned int* __restrict__ mask) {
    const int w    = threadIdx.x >> 6;
    const int lane = threadIdx.x & 63;
    const size_t row = (size_t)blockIdx.x * 4 + w;
    const int* ar = adj + (row << 11) + (lane << 5);
    int4 v[8];
#pragma unroll
    for (int k = 0; k < 8; ++k) v[k] = *(const int4*)(ar + (k << 2));
    unsigned int word = 0u;
#pragma unroll
    for (int k = 0; k < 8; ++k) {
        word |= (v[k].x > 0 ? 1u : 0u) << ((k << 2) + 0);
        word |= (v[k].y > 0 ? 1u : 0u) << ((k << 2) + 1);
        word |= (v[k].z > 0 ? 1u : 0u) << ((k << 2) + 2);
        word |= (v[k].w > 0 ? 1u : 0u) << ((k << 2) + 3);
    }
    mask[(row << 6) + lane] = word;
}

// ---------------- stage 2: fused masked-softmax attention ------------------
// Block = 128 rows x 32-o quarter (512 blocks). Mask words hoisted per
// 4-c phase (one int4 per t per lane: 8 independent 16B loads in flight,
// 32 loads/wave total for the whole j-loop). acc = 64 VGPR (no spill).
__global__ __launch_bounds__(256, 2) void gat_s6(
        const unsigned int* __restrict__ mask, const unsigned short* __restrict__ ht,
        const float* __restrict__ f1, const float* __restrict__ f2,
        float* __restrict__ out) {
    const int bk   = blockIdx.x;        // 0..511
    const int b    = bk & 7;            // batch fastest -> per-XCD L2 locality
    const int it   = (bk >> 3) & 15;
    const int oq   = bk >> 7;           // o-quarter
    const int i0   = it << 7;           // 128 rows
    const int ob   = oq << 5;           // 32 o
    const int tid  = threadIdx.x;
    const int w    = tid >> 6;          // j-quarter
    const int lane = tid & 63;
    const int m    = lane & 15;
    const int quad = lane >> 4;

    __shared__ float accb[128][33];     // 16.9 KB, post-loop only
    __shared__ float sbuf[4][8][16];

    int Mlab[4], Nlab[4];
    mfma_calib(m, quad, Mlab, Nlab);

    const int gi0 = (b << 11) + i0;
    float f1v[8];
#pragma unroll
    for (int t = 0; t < 8; ++t) f1v[t] = f1[gi0 + (t << 4) + m];
    // mask base for this lane's rows: word offset = row*64 + w*16 (+c)
    const unsigned int* mbase = mask + (((size_t)(gi0 + m)) << 6) + (w << 4);
    const float* f2b = f2 + (b << 11);
    const unsigned short* ht0 = ht + ((size_t)b << 18) + ((size_t)(ob + m) << 11);
    const unsigned short* ht1 = ht0 + (16 << 11);

    f32x4 zz = {0.f, 0.f, 0.f, 0.f};
    f32x4 acc[8][2];
#pragma unroll
    for (int t = 0; t < 8; ++t) { acc[t][0] = zz; acc[t][1] = zz; }
    float sp[8] = {0.f, 0.f, 0.f, 0.f, 0.f, 0.f, 0.f, 0.f};

    const int jb = (w << 9) + (quad << 3);
    const int sh = quad << 3;
#pragma unroll
    for (int ph = 0; ph < 4; ++ph) {
        // hoisted mask words for c = 4*ph .. 4*ph+3, all 8 t (independent loads)
        uint4 mw4[8];
#pragma unroll
        for (int t = 0; t < 8; ++t)
            mw4[t] = *(const uint4*)(mbase + (t << 10) + (ph << 2));
        const unsigned int* mwp = (const unsigned int*)mw4;

#pragma unroll
        for (int cc = 0; cc < 4; ++cc) {
            const int c  = (ph << 2) + cc;
            const int j0 = jb + (c << 5);
            short8 hf0 = *(const short8*)(ht0 + j0);
            short8 hf1 = *(const short8*)(ht1 + j0);
            float4 fa = *(const float4*)(f2b + j0);
            float4 fb = *(const float4*)(f2b + j0 + 4);
            float fm[8] = {fa.x, fa.y, fa.z, fa.w, fb.x, fb.y, fb.z, fb.w};

#pragma unroll
            for (int t = 0; t < 8; ++t) {
                const unsigned int mw = mwp[(t << 2) + cc];
                const float f1r = f1v[t];
                float p[8];
#pragma unroll
                for (int u = 0; u < 8; ++u) {
                    float e = f1r + fm[u];
                    float lr = fmaxf(e, 0.2f * e);
                    p[u] = ((mw >> (sh + u)) & 1u) ? __expf(lr) : 0.f;
                }
                sp[t] += ((p[0] + p[1]) + (p[2] + p[3])) + ((p[4] + p[5]) + (p[6] + p[7]));
                short8 pf;
#pragma unroll
                for (int u = 0; u < 8; ++u) pf[u] = (short)rbf(p[u]);
                acc[t][0] = __builtin_amdgcn_mfma_f32_16x16x32_bf16(pf, hf0, acc[t][0], 0, 0, 0);
                acc[t][1] = __builtin_amdgcn_mfma_f32_16x16x32_bf16(pf, hf1, acc[t][1], 0, 0, 0);
            }
        }
    }

    // denominators: quad-reduce per tile, stash per wave
#pragma unroll
    for (int t = 0; t < 8; ++t) {
        float v = sp[t];
        v += __shfl_xor(v, 16); v += __shfl_xor(v, 32);
        if (lane < 16) sbuf[w][t][lane] = v;
    }

    // rotating 4-phase combine: phase p, wave w handles region g=(w+p)&3
    // = rows [g*32,+32) = tiles {2g, 2g+1}; disjoint per phase.
#pragma unroll
    for (int p = 0; p < 4; ++p) {
        const int g = (w + p) & 3;
#pragma unroll
        for (int tt = 0; tt < 2; ++tt) {
            const int t = (g << 1) + tt;
            if (p == 0) {
#pragma unroll
                for (int r = 0; r < 4; ++r) {
                    accb[(t << 4) + Mlab[r]][Nlab[r]]      = acc[t][0][r];
                    accb[(t << 4) + Mlab[r]][16 + Nlab[r]] = acc[t][1][r];
                }
            } else {
#pragma unroll
                for (int r = 0; r < 4; ++r) {
                    accb[(t << 4) + Mlab[r]][Nlab[r]]      += acc[t][0][r];
                    accb[(t << 4) + Mlab[r]][16 + Nlab[r]] += acc[t][1][r];
                }
            }
        }
        __syncthreads();
    }

    // normalize + ELU + store: thread -> (row = tid>>1, 16-o half)
    {
        const int row = tid >> 1;
        const int ol  = (tid & 1) << 4;
        const int t   = row >> 4;
        const int mm  = row & 15;
        const float s = (sbuf[0][t][mm] + sbuf[1][t][mm]) +
                        (sbuf[2][t][mm] + sbuf[3][t][mm]);
        const float inv = 1.0f / s;
        float* orow = out + (((size_t)gi0 + row) << 7) + ob + ol;
#pragma unroll
        for (int v4 = 0; v4 < 4; ++v4) {
            float4 rv;
            float y;
            y = accb[row][ol + 4 * v4 + 0] * inv; rv.x = y > 0.f ? y : expm1f(y);
            y = accb[row][ol + 4 * v4 + 1] * inv; rv.y = y > 0.f ? y : expm1f(y);
            y = accb[row][ol + 4 * v4 + 2] * inv; rv.z = y > 0.f ? y : expm1f(y);
            y = accb[row][ol + 4 * v4 + 3] * inv; rv.w = y > 0.f ? y : expm1f(y);
            *(float4*)(orow + 4 * v4) = rv;
        }
    }
}

extern "C" void kernel_launch(void* const* d_in, const int* in_sizes, int n_in,
                              void* d_out, int out_size, void* d_ws, size_t ws_size,
                              hipStream_t stream) {
    const float* x   = nullptr;
    const int*   adj = nullptr;
    const float* W   = nullptr;
    const float* a   = nullptr;
    for (int i = 0; i < n_in; ++i) {
        const long s = in_sizes[i];
        if      (s == (long)BB * NN * NN)  adj = (const int*)d_in[i];
        else if (s == (long)BB * NN * FIN) x   = (const float*)d_in[i];
        else if (s == (long)FIN * FOUT)    W   = (const float*)d_in[i];
        else if (s == 2L * FOUT)           a   = (const float*)d_in[i];
    }
    if (!x)   x   = (const float*)d_in[0];
    if (!adj) adj = (const int*)d_in[1];
    if (!W)   W   = (const float*)d_in[2];
    if (!a)   a   = (const float*)d_in[3];
    float* out = (float*)d_out;

    unsigned short* wt = (unsigned short*)d_ws;            // 64 KB   W^T bf16
    unsigned short* ht = wt + 32768;                       // 4 MB    h^T bf16 [B][128][N]
    float* f1 = (float*)(ht + (size_t)BB * NN * FOUT);     // 64 KB
    float* f2 = f1 + BB * NN;                              // 64 KB
    unsigned int* mask = (unsigned int*)(f2 + BB * NN);    // 4 MB    adj bitmask

    hipLaunchKernelGGL(gat_wt, dim3(32),   dim3(256), 0, stream, W, wt);
    hipLaunchKernelGGL(gat_pk, dim3(4096), dim3(256), 0, stream, adj, mask);
    hipLaunchKernelGGL(gat_h3, dim3(1024), dim3(256), 0, stream, x, wt, a, ht, f1, f2);
    hipLaunchKernelGGL(gat_s6, dim3(512),  dim3(256), 0, stream, mask, ht, f1, f2, out);
}

// Round 11
// 280.727 us; speedup vs baseline: 1.9960x; 1.9960x over previous
//
#include <hip/hip_runtime.h>
#include <stdint.h>

#define BB   8
#define NN   2048
#define FIN  256
#define FOUT 128

using short8 = __attribute__((ext_vector_type(8))) short;
using f32x4  = __attribute__((ext_vector_type(4))) float;

__device__ __forceinline__ unsigned short rbf(float f) {
    return (unsigned short)((__float_as_uint(f) + 0x8000u) >> 16);
}

// Calibration: 2 probe MFMAs read off the true (row,col) label of each
// accumulator element (validated round 4). Epilogues index by these labels.
__device__ __forceinline__ void mfma_calib(int m, int quad, int* Mlab, int* Nlab) {
    short8 pa1, pb1, pa2, pb2;
    const short one = (short)0x3F80;            // bf16 1.0
    const short mb  = (short)rbf((float)m);     // bf16 m (exact, m<16)
#pragma unroll
    for (int j = 0; j < 8; ++j) { pa1[j] = 0; pa2[j] = 0; pb1[j] = mb; pb2[j] = one; }
    if (quad == 0) { pa1[0] = one; pa2[0] = mb; }
    f32x4 zz = {0.f, 0.f, 0.f, 0.f};
    f32x4 c1 = __builtin_amdgcn_mfma_f32_16x16x32_bf16(pa1, pb1, zz, 0, 0, 0);
    f32x4 c2 = __builtin_amdgcn_mfma_f32_16x16x32_bf16(pa2, pb2, zz, 0, 0, 0);
#pragma unroll
    for (int r = 0; r < 4; ++r) {
        Nlab[r] = ((int)c1[r]) & 15;
        Mlab[r] = ((int)c2[r]) & 15;
    }
}

// ---------------- W[256][128] fp32 -> wt[128][256] bf16 (W^T) --------------
__global__ __launch_bounds__(256) void gat_wt(const float* __restrict__ W,
                                              unsigned short* __restrict__ wt) {
    const int g  = blockIdx.x * 256 + threadIdx.x;
    const int k  = g >> 5;
    const int o4 = (g & 31) << 2;
    float4 wv = *(const float4*)(W + (k << 7) + o4);
    wt[((o4 + 0) << 8) + k] = rbf(wv.x);
    wt[((o4 + 1) << 8) + k] = rbf(wv.y);
    wt[((o4 + 2) << 8) + k] = rbf(wv.z);
    wt[((o4 + 3) << 8) + k] = rbf(wv.w);
}

// ---------------- stage 1: h = x@W via MFMA (16 rows/block) ----------------
__global__ __launch_bounds__(256) void gat_h3(
        const float* __restrict__ x, const unsigned short* __restrict__ wt,
        const float* __restrict__ a, unsigned short* __restrict__ ht,
        float* __restrict__ f1, float* __restrict__ f2) {
    __shared__ unsigned short xs[16][264];
    __shared__ float hs[16][132];
    const int bk   = blockIdx.x;
    const int R0   = bk << 4;
    const int b    = R0 >> 11;
    const int il0  = R0 & (NN - 1);
    const int tid  = threadIdx.x;
    const int w    = tid >> 6;
    const int lane = tid & 63;
    const int m    = lane & 15;
    const int quad = lane >> 4;

#pragma unroll
    for (int rr = 0; rr < 4; ++rr) {
        const int row = (w << 2) + rr;
        float4 xv = *(const float4*)(x + (size_t)(R0 + row) * FIN + (lane << 2));
        ushort4 c4;
        c4.x = rbf(xv.x); c4.y = rbf(xv.y); c4.z = rbf(xv.z); c4.w = rbf(xv.w);
        *(ushort4*)(&xs[row][lane << 2]) = c4;
    }
    int Mlab[4], Nlab[4];
    mfma_calib(m, quad, Mlab, Nlab);
    __syncthreads();

    f32x4 zz = {0.f, 0.f, 0.f, 0.f};
    f32x4 acc[2] = {zz, zz};
#pragma unroll
    for (int kc = 0; kc < 8; ++kc) {
        const int k0 = (kc << 5) + (quad << 3);
        short8 av = *(const short8*)(&xs[m][k0]);
#pragma unroll
        for (int t = 0; t < 2; ++t) {
            const int ot = (w << 1) + t;
            short8 bw = *(const short8*)(wt + (((ot << 4) + m) << 8) + k0);
            acc[t] = __builtin_amdgcn_mfma_f32_16x16x32_bf16(av, bw, acc[t], 0, 0, 0);
        }
    }
#pragma unroll
    for (int t = 0; t < 2; ++t)
#pragma unroll
        for (int r = 0; r < 4; ++r)
            hs[Mlab[r]][(((w << 1) + t) << 4) + Nlab[r]] = acc[t][r];
    __syncthreads();

    {
        const int i   = tid >> 4;
        const int seg = tid & 15;
        const int o0  = seg << 3;
        float s1 = 0.f, s2 = 0.f;
#pragma unroll
        for (int e = 0; e < 8; ++e) {
            float hv = hs[i][o0 + e];
            s1 = fmaf(hv, a[o0 + e], s1);
            s2 = fmaf(hv, a[FOUT + o0 + e], s2);
        }
        s1 += __shfl_xor(s1, 1); s1 += __shfl_xor(s1, 2);
        s1 += __shfl_xor(s1, 4); s1 += __shfl_xor(s1, 8);
        s2 += __shfl_xor(s2, 1); s2 += __shfl_xor(s2, 2);
        s2 += __shfl_xor(s2, 4); s2 += __shfl_xor(s2, 8);
        if (seg == 0) { f1[R0 + i] = s1; f2[R0 + i] = s2; }
    }
    {
        const int o  = tid >> 1;
        const int i8 = (tid & 1) << 3;
        short8 hv;
#pragma unroll
        for (int e = 0; e < 8; ++e) hv[e] = (short)rbf(hs[i8 + e][o]);
        *(short8*)(ht + ((size_t)((b << 7) + o) << 11) + il0 + i8) = hv;
    }
}

// ---------------- adj pack: int32 0/1 -> bitmask ---------------------------
// Lane owns 32 contiguous ints (8 independent int4 loads in flight, no
// cross-lane ops), builds its own mask word; coalesced 256B word stores.
__global__ __launch_bounds__(256) void gat_pk(const int* __restrict__ adj,
                                              unsigned int* __restrict__ mask) {
    const int w    = threadIdx.x >> 6;
    const int lane = threadIdx.x & 63;
    const size_t row = (size_t)blockIdx.x * 4 + w;
    const int* ar = adj + (row << 11) + (lane << 5);
    int4 v[8];
#pragma unroll
    for (int k = 0; k < 8; ++k) v[k] = *(const int4*)(ar + (k << 2));
    unsigned int word = 0u;
#pragma unroll
    for (int k = 0; k < 8; ++k) {
        word |= (v[k].x > 0 ? 1u : 0u) << ((k << 2) + 0);
        word |= (v[k].y > 0 ? 1u : 0u) << ((k << 2) + 1);
        word |= (v[k].z > 0 ? 1u : 0u) << ((k << 2) + 2);
        word |= (v[k].w > 0 ? 1u : 0u) << ((k << 2) + 3);
    }
    mask[(row << 6) + lane] = word;
}

// ---------------- stage 2: fused masked-softmax attention ------------------
// Block = 128 rows x 32-o quarter (512 blocks). Block's mask slice (32 KB)
// cooperatively staged to LDS once (stride-65 padded, conflict-free); in-loop
// mask access = ds_read_b32. accb OVERLAYS the mask region (live only after
// the j-loop; barrier guards the overlay). No private-array pointer casts.
__global__ __launch_bounds__(256, 2) void gat_s7(
        const unsigned int* __restrict__ mask, const unsigned short* __restrict__ ht,
        const float* __restrict__ f1, const float* __restrict__ f2,
        float* __restrict__ out) {
    alignas(16) __shared__ char smem[35328];
    unsigned int* mlds = (unsigned int*)smem;          // [128][65] words, j-loop only
    float (*accb)[33]  = (float (*)[33])smem;          // [128][33], post-loop overlay
    float* sbuf        = (float*)(smem + 33280);       // [4][8][16]

    const int bk   = blockIdx.x;        // 0..511
    const int b    = bk & 7;            // batch fastest -> per-XCD L2 locality
    const int it   = (bk >> 3) & 15;
    const int oq   = bk >> 7;           // o-quarter
    const int i0   = it << 7;           // 128 rows
    const int ob   = oq << 5;           // 32 o
    const int tid  = threadIdx.x;
    const int w    = tid >> 6;          // j-quarter
    const int lane = tid & 63;
    const int m    = lane & 15;
    const int quad = lane >> 4;

    const int gi0 = (b << 11) + i0;

    // ---- cooperative mask stage: 128 rows x 64 words, coalesced uint4 ----
    {
        const unsigned int* msrc = mask + ((size_t)gi0 << 6);
#pragma unroll
        for (int k = 0; k < 8; ++k) {
            const int idx = (k << 8) + tid;      // 0..2047
            const int row = idx >> 4;
            const int c4  = (idx & 15) << 2;
            uint4 v = *(const uint4*)(msrc + (row << 6) + c4);
            mlds[row * 65 + c4 + 0] = v.x;
            mlds[row * 65 + c4 + 1] = v.y;
            mlds[row * 65 + c4 + 2] = v.z;
            mlds[row * 65 + c4 + 3] = v.w;
        }
    }

    int Mlab[4], Nlab[4];
    mfma_calib(m, quad, Mlab, Nlab);

    float f1v[8];
#pragma unroll
    for (int t = 0; t < 8; ++t) f1v[t] = f1[gi0 + (t << 4) + m];
    const float* f2b = f2 + (b << 11);
    const unsigned short* ht0 = ht + ((size_t)b << 18) + ((size_t)(ob + m) << 11);
    const unsigned short* ht1 = ht0 + (16 << 11);

    __syncthreads();   // mask staged

    f32x4 zz = {0.f, 0.f, 0.f, 0.f};
    f32x4 acc[8][2];
#pragma unroll
    for (int t = 0; t < 8; ++t) { acc[t][0] = zz; acc[t][1] = zz; }
    float sp[8] = {0.f, 0.f, 0.f, 0.f, 0.f, 0.f, 0.f, 0.f};

    const int jb = (w << 9) + (quad << 3);
    const int sh = quad << 3;
#pragma unroll 4
    for (int c = 0; c < 16; ++c) {
        const int j0 = jb + (c << 5);
        short8 hf0 = *(const short8*)(ht0 + j0);
        short8 hf1 = *(const short8*)(ht1 + j0);
        float4 fa = *(const float4*)(f2b + j0);
        float4 fb = *(const float4*)(f2b + j0 + 4);
        float fm[8] = {fa.x, fa.y, fa.z, fa.w, fb.x, fb.y, fb.z, fb.w};

#pragma unroll
        for (int t = 0; t < 8; ++t) {
            const unsigned int mw = mlds[((t << 4) + m) * 65 + (w << 4) + c];
            const float f1r = f1v[t];
            float p[8];
#pragma unroll
            for (int u = 0; u < 8; ++u) {
                float e = f1r + fm[u];
                float lr = fmaxf(e, 0.2f * e);
                p[u] = ((mw >> (sh + u)) & 1u) ? __expf(lr) : 0.f;
            }
            sp[t] += ((p[0] + p[1]) + (p[2] + p[3])) + ((p[4] + p[5]) + (p[6] + p[7]));
            short8 pf;
#pragma unroll
            for (int u = 0; u < 8; ++u) pf[u] = (short)rbf(p[u]);
            acc[t][0] = __builtin_amdgcn_mfma_f32_16x16x32_bf16(pf, hf0, acc[t][0], 0, 0, 0);
            acc[t][1] = __builtin_amdgcn_mfma_f32_16x16x32_bf16(pf, hf1, acc[t][1], 0, 0, 0);
        }
    }

    // denominators: quad-reduce per tile, stash per wave (sbuf is NOT overlaid)
#pragma unroll
    for (int t = 0; t < 8; ++t) {
        float v = sp[t];
        v += __shfl_xor(v, 16); v += __shfl_xor(v, 32);
        if (lane < 16) sbuf[(w << 7) + (t << 4) + lane] = v;
    }
    __syncthreads();   // all waves done reading mlds -> accb overlay safe

    // rotating 4-phase combine: phase p, wave w handles region g=(w+p)&3
    // = rows [g*32,+32) = tiles {2g, 2g+1}; disjoint per phase.
#pragma unroll
    for (int p = 0; p < 4; ++p) {
        const int g = (w + p) & 3;
#pragma unroll
        for (int tt = 0; tt < 2; ++tt) {
            const int t = (g << 1) + tt;
            if (p == 0) {
#pragma unroll
                for (int r = 0; r < 4; ++r) {
                    accb[(t << 4) + Mlab[r]][Nlab[r]]      = acc[t][0][r];
                    accb[(t << 4) + Mlab[r]][16 + Nlab[r]] = acc[t][1][r];
                }
            } else {
#pragma unroll
                for (int r = 0; r < 4; ++r) {
                    accb[(t << 4) + Mlab[r]][Nlab[r]]      += acc[t][0][r];
                    accb[(t << 4) + Mlab[r]][16 + Nlab[r]] += acc[t][1][r];
                }
            }
        }
        __syncthreads();
    }

    // normalize + ELU + store: thread -> (row = tid>>1, 16-o half)
    {
        const int row = tid >> 1;
        const int ol  = (tid & 1) << 4;
        const int t   = row >> 4;
        const int mm  = row & 15;
        const float s = (sbuf[(t << 4) + mm] + sbuf[128 + (t << 4) + mm]) +
                        (sbuf[256 + (t << 4) + mm] + sbuf[384 + (t << 4) + mm]);
        const float inv = 1.0f / s;
        float* orow = out + (((size_t)gi0 + row) << 7) + ob + ol;
#pragma unroll
        for (int v4 = 0; v4 < 4; ++v4) {
            float4 rv;
            float y;
            y = accb[row][ol + 4 * v4 + 0] * inv; rv.x = y > 0.f ? y : expm1f(y);
            y = accb[row][ol + 4 * v4 + 1] * inv; rv.y = y > 0.f ? y : expm1f(y);
            y = accb[row][ol + 4 * v4 + 2] * inv; rv.z = y > 0.f ? y : expm1f(y);
            y = accb[row][ol + 4 * v4 + 3] * inv; rv.w = y > 0.f ? y : expm1f(y);
            *(float4*)(orow + 4 * v4) = rv;
        }
    }
}

extern "C" void kernel_launch(void* const* d_in, const int* in_sizes, int n_in,
                              void* d_out, int out_size, void* d_ws, size_t ws_size,
                              hipStream_t stream) {
    const float* x   = nullptr;
    const int*   adj = nullptr;
    const float* W   = nullptr;
    const float* a   = nullptr;
    for (int i = 0; i < n_in; ++i) {
        const long s = in_sizes[i];
        if      (s == (long)BB * NN * NN)  adj = (const int*)d_in[i];
        else if (s == (long)BB * NN * FIN) x   = (const float*)d_in[i];
        else if (s == (long)FIN * FOUT)    W   = (const float*)d_in[i];
        else if (s == 2L * FOUT)           a   = (const float*)d_in[i];
    }
    if (!x)   x   = (const float*)d_in[0];
    if (!adj) adj = (const int*)d_in[1];
    if (!W)   W   = (const float*)d_in[2];
    if (!a)   a   = (const float*)d_in[3];
    float* out = (float*)d_out;

    unsigned short* wt = (unsigned short*)d_ws;            // 64 KB   W^T bf16
    unsigned short* ht = wt + 32768;                       // 4 MB    h^T bf16 [B][128][N]
    float* f1 = (float*)(ht + (size_t)BB * NN * FOUT);     // 64 KB
    float* f2 = f1 + BB * NN;                              // 64 KB
    unsigned int* mask = (unsigned int*)(f2 + BB * NN);    // 4 MB    adj bitmask

    hipLaunchKernelGGL(gat_wt, dim3(32),   dim3(256), 0, stream, W, wt);
    hipLaunchKernelGGL(gat_pk, dim3(4096), dim3(256), 0, stream, adj, mask);
    hipLaunchKernelGGL(gat_h3, dim3(1024), dim3(256), 0, stream, x, wt, a, ht, f1, f2);
    hipLaunchKernelGGL(gat_s7, dim3(512),  dim3(256), 0, stream, mask, ht, f1, f2, out);
}